// Round 1
// baseline (15625.432 us; speedup 1.0000x reference)
//
#include <hip/hip_runtime.h>
#include <math.h>

#define NN   2048
#define NLVL 7
#define HD   16
#define HTOT 112
#define NB   64

// ---------------- build K = lap_kernel(xt,xt,sigma) + alpha*I ----------------
__global__ __launch_bounds__(256) void build_K(
    const float* __restrict__ tp, const float* __restrict__ alpha,
    const float* __restrict__ sigma, float* __restrict__ K, int lvl0)
{
  int lz  = blockIdx.y;
  int lvl = lvl0 + lz;
  int idx = blockIdx.x * 256 + threadIdx.x;       // < NN*NN
  int i = idx >> 11, j = idx & (NN - 1);
  const float* xt = tp + (size_t)lvl * NN * 3;
  float xi0 = xt[i*3+0], xi1 = xt[i*3+1], xi2 = xt[i*3+2];
  float xj0 = xt[j*3+0], xj1 = xt[j*3+1], xj2 = xt[j*3+2];
  float d0 = xi0-xj0, d1 = xi1-xj1, d2 = xi2-xj2;
  float dd = d0*d0 + d1*d1 + d2*d2;
  float v = __expf(-sqrtf(fmaxf(dd, 1e-12f)) / sigma[lvl]);
  if (i == j) v += alpha[lvl];
  K[(size_t)lz*NN*NN + idx] = v;
}

// ---------------- Cholesky: 64x64 diagonal block factor (1 wave) ----------------
__global__ __launch_bounds__(64) void chol_diag(float* __restrict__ K, int k)
{
  int lz = blockIdx.x;
  float* A = K + (size_t)lz * NN * NN;
  __shared__ float s[64][65];
  int tid = threadIdx.x;
  #pragma unroll 4
  for (int r = 0; r < 64; ++r)
    s[r][tid] = A[(size_t)(k + r) * NN + k + tid];
  __syncthreads();
  for (int j = 0; j < 64; ++j) {
    float djj = s[j][j];                // squared pivot (diag deferred)
    float inv = 1.0f / sqrtf(djj);
    if (tid > j) s[tid][j] *= inv;
    __syncthreads();
    if (tid > j) {
      float fr = s[tid][j];
      for (int p = j + 1; p <= tid; ++p)
        s[tid][p] -= fr * s[p][j];
    }
    __syncthreads();
  }
  s[tid][tid] = sqrtf(s[tid][tid]);
  __syncthreads();
  #pragma unroll 4
  for (int r = 0; r < 64; ++r)
    A[(size_t)(k + r) * NN + k + tid] = s[r][tid];
}

// ---------------- Cholesky: panel TRSM  A21 <- A21 * L11^-T ----------------
__global__ __launch_bounds__(128) void panel_trsm(float* __restrict__ K, int k)
{
  int lz = blockIdx.y;
  float* A = K + (size_t)lz * NN * NN;
  __shared__ float Ld[64][65];
  __shared__ float invd[64];
  __shared__ float P[128][65];
  int tid = threadIdx.x;
  for (int t = tid; t < 4096; t += 128)
    Ld[t >> 6][t & 63] = A[(size_t)(k + (t >> 6)) * NN + k + (t & 63)];
  int rbase = k + NB + blockIdx.x * 128;
  for (int t = tid; t < 128 * 64; t += 128) {
    int r = t >> 6, c = t & 63;
    if (rbase + r < NN) P[r][c] = A[(size_t)(rbase + r) * NN + k + c];
  }
  __syncthreads();
  if (tid < 64) invd[tid] = 1.0f / Ld[tid][tid];
  __syncthreads();
  int r = tid;
  if (rbase + r < NN) {
    for (int j = 0; j < 64; ++j) {
      float acc = P[r][j];
      for (int p = 0; p < j; ++p) acc -= Ld[j][p] * P[r][p];
      P[r][j] = acc * invd[j];
    }
  }
  __syncthreads();
  for (int t = tid; t < 128 * 64; t += 128) {
    int rr = t >> 6, c = t & 63;
    if (rbase + rr < NN) A[(size_t)(rbase + rr) * NN + k + c] = P[rr][c];
  }
}

// ---------------- Cholesky: trailing update  A22 -= L21 * L21^T ----------------
__global__ __launch_bounds__(256) void syrk_update(float* __restrict__ K, int k)
{
  if (blockIdx.y > blockIdx.x) return;          // lower tiles only
  int lz = blockIdx.z;
  float* A = K + (size_t)lz * NN * NN;
  int i0 = k + NB + blockIdx.x * 64;
  int j0 = k + NB + blockIdx.y * 64;
  __shared__ __align__(16) float Asub[64][68];
  __shared__ __align__(16) float Bsub[64][68];
  int tid = threadIdx.x;
  for (int t = tid; t < 4096; t += 256) {
    int r = t >> 6, c = t & 63;
    Asub[r][c] = A[(size_t)(i0 + r) * NN + k + c];
    Bsub[r][c] = A[(size_t)(j0 + r) * NN + k + c];
  }
  __syncthreads();
  int tx = tid & 15, ty = tid >> 4;
  float acc[4][4] = {{0.f}};
  #pragma unroll
  for (int p4 = 0; p4 < 16; ++p4) {
    float4 av[4], bv[4];
    #pragma unroll
    for (int ii = 0; ii < 4; ++ii) av[ii] = *(const float4*)&Asub[ty*4+ii][p4*4];
    #pragma unroll
    for (int jj = 0; jj < 4; ++jj) bv[jj] = *(const float4*)&Bsub[tx*4+jj][p4*4];
    #pragma unroll
    for (int ii = 0; ii < 4; ++ii)
      #pragma unroll
      for (int jj = 0; jj < 4; ++jj)
        acc[ii][jj] += av[ii].x*bv[jj].x + av[ii].y*bv[jj].y
                     + av[ii].z*bv[jj].z + av[ii].w*bv[jj].w;
  }
  #pragma unroll
  for (int ii = 0; ii < 4; ++ii) {
    int row = i0 + ty*4 + ii;
    float4* cp = (float4*)&A[(size_t)row * NN + j0 + tx*4];
    float4 cv = *cp;
    cv.x -= acc[ii][0]; cv.y -= acc[ii][1]; cv.z -= acc[ii][2]; cv.w -= acc[ii][3];
    *cp = cv;
  }
}

// ---------------- forward solve  L y = W  (in place on Y) ----------------
__global__ __launch_bounds__(512) void trsm_fwd(const float* __restrict__ K, float* __restrict__ Y)
{
  int lz = blockIdx.x;
  const float* L = K + (size_t)lz * NN * NN;
  float* y = Y + (size_t)lz * NN * HD;
  __shared__ float Ld[64][65];
  __shared__ float yb[64][HD];
  int tid = threadIdx.x;
  for (int kb = 0; kb < NN; kb += 64) {
    for (int t = tid; t < 4096; t += 512)
      Ld[t >> 6][t & 63] = L[(size_t)(kb + (t >> 6)) * NN + kb + (t & 63)];
    for (int t = tid; t < 64 * HD; t += 512)
      yb[t >> 4][t & 15] = y[(size_t)kb * HD + t];
    __syncthreads();
    if (tid < HD) {
      int c = tid;
      for (int j = 0; j < 64; ++j) {
        float acc = yb[j][c];
        for (int p = 0; p < j; ++p) acc -= Ld[j][p] * yb[p][c];
        yb[j][c] = acc / Ld[j][j];
      }
    }
    __syncthreads();
    for (int t = tid; t < 64 * HD; t += 512)
      y[(size_t)kb * HD + t] = yb[t >> 4][t & 15];
    int rl = tid >> 4, c = tid & 15;
    for (int r0 = kb + 64; r0 < NN; r0 += 32) {
      int r = r0 + rl;
      float acc = y[(size_t)r * HD + c];
      #pragma unroll 16
      for (int p = 0; p < 64; ++p)
        acc -= L[(size_t)r * NN + kb + p] * yb[p][c];
      y[(size_t)r * HD + c] = acc;
    }
    __syncthreads();
  }
}

// ---------------- backward solve  L^T a = y  (in place on Y) ----------------
__global__ __launch_bounds__(512) void trsm_bwd(const float* __restrict__ K, float* __restrict__ Y)
{
  int lz = blockIdx.x;
  const float* L = K + (size_t)lz * NN * NN;
  float* y = Y + (size_t)lz * NN * HD;
  __shared__ float Ld[64][65];
  __shared__ float yb[64][HD];
  int tid = threadIdx.x;
  for (int kb = NN - 64; kb >= 0; kb -= 64) {
    for (int t = tid; t < 4096; t += 512)
      Ld[t >> 6][t & 63] = L[(size_t)(kb + (t >> 6)) * NN + kb + (t & 63)];
    for (int t = tid; t < 64 * HD; t += 512)
      yb[t >> 4][t & 15] = y[(size_t)kb * HD + t];
    __syncthreads();
    if (tid < HD) {
      int c = tid;
      for (int j = 63; j >= 0; --j) {
        float acc = yb[j][c];
        for (int p = j + 1; p < 64; ++p) acc -= Ld[p][j] * yb[p][c];
        yb[j][c] = acc / Ld[j][j];
      }
    }
    __syncthreads();
    for (int t = tid; t < 64 * HD; t += 512)
      y[(size_t)kb * HD + t] = yb[t >> 4][t & 15];
    int rl = tid >> 4, c = tid & 15;
    for (int r0 = 0; r0 < kb; r0 += 32) {
      int r = r0 + rl;
      float acc = y[(size_t)r * HD + c];
      #pragma unroll 16
      for (int p = 0; p < 64; ++p)
        acc -= L[(size_t)(kb + p) * NN + r] * yb[p][c];
      y[(size_t)r * HD + c] = acc;
    }
    __syncthreads();
  }
}

// ---------------- fused h^T[l*16+hh][i] = (K_tx @ a)  ----------------
__global__ __launch_bounds__(256) void compute_h(
    const float* __restrict__ x, const float* __restrict__ tp,
    const float* __restrict__ A, const float* __restrict__ sigma,
    float* __restrict__ Ht, int N)
{
  int l = blockIdx.y;
  const float* xt = tp + (size_t)l * NN * 3;
  const float* al = A + (size_t)l * NN * HD;
  float inv_sigma = 1.0f / sigma[l];
  int tid = threadIdx.x;
  int r0 = blockIdx.x * 512 + tid;
  int r1 = r0 + 256;
  float x00=0.f,x01=0.f,x02=0.f, x10=0.f,x11=0.f,x12=0.f;
  if (r0 < N) { x00 = x[r0*3]; x01 = x[r0*3+1]; x02 = x[r0*3+2]; }
  if (r1 < N) { x10 = x[r1*3]; x11 = x[r1*3+1]; x12 = x[r1*3+2]; }
  __shared__ float sxt[128*3];
  __shared__ __align__(16) float sa[128*16];
  float acc0[16] = {0.f}; float acc1[16] = {0.f};
  for (int jc = 0; jc < NN; jc += 128) {
    __syncthreads();
    for (int t = tid; t < 384; t += 256)  sxt[t] = xt[jc*3 + t];
    for (int t = tid; t < 2048; t += 256) sa[t]  = al[jc*16 + t];
    __syncthreads();
    for (int jl = 0; jl < 128; ++jl) {
      float t0 = sxt[jl*3+0], t1 = sxt[jl*3+1], t2 = sxt[jl*3+2];
      float da = x00 - t0, db = x01 - t1, dc = x02 - t2;
      float d20 = da*da + db*db + dc*dc;
      da = x10 - t0; db = x11 - t1; dc = x12 - t2;
      float d21 = da*da + db*db + dc*dc;
      float k0 = __expf(-sqrtf(fmaxf(d20, 1e-12f)) * inv_sigma);
      float k1 = __expf(-sqrtf(fmaxf(d21, 1e-12f)) * inv_sigma);
      const float4* a4 = (const float4*)&sa[jl*16];
      #pragma unroll
      for (int q = 0; q < 4; ++q) {
        float4 av = a4[q];
        acc0[q*4+0] += k0*av.x; acc0[q*4+1] += k0*av.y;
        acc0[q*4+2] += k0*av.z; acc0[q*4+3] += k0*av.w;
        acc1[q*4+0] += k1*av.x; acc1[q*4+1] += k1*av.y;
        acc1[q*4+2] += k1*av.z; acc1[q*4+3] += k1*av.w;
      }
    }
  }
  if (r0 < N) {
    #pragma unroll
    for (int hh = 0; hh < 16; ++hh) Ht[(size_t)(l*HD + hh) * N + r0] = acc0[hh];
  }
  if (r1 < N) {
    #pragma unroll
    for (int hh = 0; hh < 16; ++hh) Ht[(size_t)(l*HD + hh) * N + r1] = acc1[hh];
  }
}

// ---------------- MLP 112->40->40->40->40->1, weights in LDS ----------------
__global__ __launch_bounds__(256) void mlp_kernel(
    const float* __restrict__ Ht,
    const float* __restrict__ w1, const float* __restrict__ b1,
    const float* __restrict__ w2, const float* __restrict__ b2,
    const float* __restrict__ w3, const float* __restrict__ b3,
    const float* __restrict__ w4, const float* __restrict__ b4,
    const float* __restrict__ w5, const float* __restrict__ b5,
    float* __restrict__ out, int N)
{
  __shared__ __align__(16) float W1[HTOT*40];
  __shared__ __align__(16) float W2[1600];
  __shared__ __align__(16) float W3[1600];
  __shared__ __align__(16) float W4[1600];
  __shared__ float W5[40], B1[40], B2[40], B3[40], B4[40];
  __shared__ float B5s;
  int tid = threadIdx.x;
  for (int t = tid; t < HTOT*40; t += 256) W1[t] = w1[t];
  for (int t = tid; t < 1600; t += 256) { W2[t] = w2[t]; W3[t] = w3[t]; W4[t] = w4[t]; }
  if (tid < 40) { B1[tid]=b1[tid]; B2[tid]=b2[tid]; B3[tid]=b3[tid]; B4[tid]=b4[tid]; W5[tid]=w5[tid]; }
  if (tid == 0) B5s = b5[0];
  __syncthreads();
  int r = blockIdx.x * 256 + tid;
  if (r >= N) return;

  float za[40], zb[40];
  #pragma unroll
  for (int o = 0; o < 40; ++o) za[o] = B1[o];
  for (int i = 0; i < HTOT; ++i) {
    float hv = Ht[(size_t)i * N + r];
    const float4* wp = (const float4*)&W1[i*40];
    #pragma unroll
    for (int q = 0; q < 10; ++q) {
      float4 wv = wp[q];
      za[q*4+0] += hv*wv.x; za[q*4+1] += hv*wv.y; za[q*4+2] += hv*wv.z; za[q*4+3] += hv*wv.w;
    }
  }
  #pragma unroll
  for (int o = 0; o < 40; ++o) { za[o] = fmaxf(za[o], 0.f); zb[o] = B2[o]; }
  for (int i = 0; i < 40; ++i) {
    float hv = za[i];
    const float4* wp = (const float4*)&W2[i*40];
    #pragma unroll
    for (int q = 0; q < 10; ++q) {
      float4 wv = wp[q];
      zb[q*4+0] += hv*wv.x; zb[q*4+1] += hv*wv.y; zb[q*4+2] += hv*wv.z; zb[q*4+3] += hv*wv.w;
    }
  }
  #pragma unroll
  for (int o = 0; o < 40; ++o) { zb[o] = fmaxf(zb[o], 0.f); za[o] = B3[o]; }
  for (int i = 0; i < 40; ++i) {
    float hv = zb[i];
    const float4* wp = (const float4*)&W3[i*40];
    #pragma unroll
    for (int q = 0; q < 10; ++q) {
      float4 wv = wp[q];
      za[q*4+0] += hv*wv.x; za[q*4+1] += hv*wv.y; za[q*4+2] += hv*wv.z; za[q*4+3] += hv*wv.w;
    }
  }
  #pragma unroll
  for (int o = 0; o < 40; ++o) { za[o] = fmaxf(za[o], 0.f); zb[o] = B4[o]; }
  for (int i = 0; i < 40; ++i) {
    float hv = za[i];
    const float4* wp = (const float4*)&W4[i*40];
    #pragma unroll
    for (int q = 0; q < 10; ++q) {
      float4 wv = wp[q];
      zb[q*4+0] += hv*wv.x; zb[q*4+1] += hv*wv.y; zb[q*4+2] += hv*wv.z; zb[q*4+3] += hv*wv.w;
    }
  }
  float ov = B5s;
  #pragma unroll
  for (int o = 0; o < 40; ++o) ov += fmaxf(zb[o], 0.f) * W5[o];
  out[r] = ov;
}

// ---------------- host ----------------
static void run_chol_steps(float* K, int nl, hipStream_t stream)
{
  for (int k = 0; k < NN; k += NB) {
    chol_diag<<<nl, 64, 0, stream>>>(K, k);
    int m = NN - k - NB;
    if (m > 0) {
      panel_trsm<<<dim3((m + 127) / 128, nl), 128, 0, stream>>>(K, k);
      int t = m / 64;
      syrk_update<<<dim3(t, t, nl), 256, 0, stream>>>(K, k);
    }
  }
}

extern "C" void kernel_launch(void* const* d_in, const int* in_sizes, int n_in,
                              void* d_out, int out_size, void* d_ws, size_t ws_size,
                              hipStream_t stream)
{
  (void)n_in; (void)out_size;
  const float* x     = (const float*)d_in[0];
  const float* tp    = (const float*)d_in[1];
  const float* W     = (const float*)d_in[2];
  const float* alpha = (const float*)d_in[3];
  const float* sigma = (const float*)d_in[4];
  const float* w1 = (const float*)d_in[5];  const float* b1 = (const float*)d_in[6];
  const float* w2 = (const float*)d_in[7];  const float* b2 = (const float*)d_in[8];
  const float* w3 = (const float*)d_in[9];  const float* b3 = (const float*)d_in[10];
  const float* w4 = (const float*)d_in[11]; const float* b4 = (const float*)d_in[12];
  const float* w5 = (const float*)d_in[13]; const float* b5 = (const float*)d_in[14];
  float* out = (float*)d_out;
  int N = in_sizes[0] / 3;

  size_t kElems1 = (size_t)NN * NN;
  size_t aElems  = (size_t)NLVL * NN * HD;
  size_t hElems  = (size_t)N * HTOT;
  size_t need7   = (7 * kElems1 + aElems + hElems) * sizeof(float);
  bool batched = ws_size >= need7;
  int nlK = batched ? NLVL : 1;

  float* K = (float*)d_ws;
  float* A = K + (size_t)nlK * kElems1;   // solve RHS, becomes 'a' in place
  float* H = A + aElems;                  // transposed h: [112][N]

  hipMemcpyAsync(A, W, aElems * sizeof(float), hipMemcpyDeviceToDevice, stream);

  if (batched) {
    build_K<<<dim3((unsigned)(kElems1 / 256), NLVL), 256, 0, stream>>>(tp, alpha, sigma, K, 0);
    run_chol_steps(K, NLVL, stream);
    trsm_fwd<<<NLVL, 512, 0, stream>>>(K, A);
    trsm_bwd<<<NLVL, 512, 0, stream>>>(K, A);
  } else {
    for (int l = 0; l < NLVL; ++l) {
      build_K<<<dim3((unsigned)(kElems1 / 256), 1), 256, 0, stream>>>(tp, alpha, sigma, K, l);
      run_chol_steps(K, 1, stream);
      trsm_fwd<<<1, 512, 0, stream>>>(K, A + (size_t)l * NN * HD);
      trsm_bwd<<<1, 512, 0, stream>>>(K, A + (size_t)l * NN * HD);
    }
  }

  compute_h<<<dim3((N + 511) / 512, NLVL), 256, 0, stream>>>(x, tp, A, sigma, H, N);
  mlp_kernel<<<(N + 255) / 256, 256, 0, stream>>>(H, w1, b1, w2, b2, w3, b3, w4, b4, w5, b5, out, N);
}

// Round 2
// 9309.177 us; speedup vs baseline: 1.6785x; 1.6785x over previous
//
#include <hip/hip_runtime.h>
#include <math.h>

#define NN   2048
#define NLVL 7
#define HD   16
#define HTOT 112
#define NB   64

// ---------------- build K = lap_kernel(xt,xt,sigma) + alpha*I ----------------
__global__ __launch_bounds__(256) void build_K(
    const float* __restrict__ tp, const float* __restrict__ alpha,
    const float* __restrict__ sigma, float* __restrict__ K, int lvl0)
{
  int lz  = blockIdx.y;
  int lvl = lvl0 + lz;
  int idx = blockIdx.x * 256 + threadIdx.x;       // < NN*NN
  int i = idx >> 11, j = idx & (NN - 1);
  const float* xt = tp + (size_t)lvl * NN * 3;
  float xi0 = xt[i*3+0], xi1 = xt[i*3+1], xi2 = xt[i*3+2];
  float xj0 = xt[j*3+0], xj1 = xt[j*3+1], xj2 = xt[j*3+2];
  float d0 = xi0-xj0, d1 = xi1-xj1, d2 = xi2-xj2;
  float dd = d0*d0 + d1*d1 + d2*d2;
  float v = __expf(-sqrtf(fmaxf(dd, 1e-12f)) / sigma[lvl]);
  if (i == j) v += alpha[lvl];
  K[(size_t)lz*NN*NN + idx] = v;
}

// ---------------- Cholesky: 64x64 diagonal block factor (1 wave) ----------------
__global__ __launch_bounds__(64) void chol_diag(float* __restrict__ K, int k)
{
  int lz = blockIdx.x;
  float* A = K + (size_t)lz * NN * NN;
  __shared__ float s[64][65];
  int tid = threadIdx.x;
  #pragma unroll 4
  for (int r = 0; r < 64; ++r)
    s[r][tid] = A[(size_t)(k + r) * NN + k + tid];
  __syncthreads();
  for (int j = 0; j < 64; ++j) {
    float djj = s[j][j];
    float inv = 1.0f / sqrtf(djj);
    if (tid > j) s[tid][j] *= inv;
    __syncthreads();
    if (tid > j) {
      float fr = s[tid][j];
      for (int p = j + 1; p <= tid; ++p)
        s[tid][p] -= fr * s[p][j];
    }
    __syncthreads();
  }
  s[tid][tid] = sqrtf(s[tid][tid]);
  __syncthreads();
  #pragma unroll 4
  for (int r = 0; r < 64; ++r)
    A[(size_t)(k + r) * NN + k + tid] = s[r][tid];
}

// ---------------- Cholesky: panel TRSM  A21 <- A21 * L11^-T ----------------
__global__ __launch_bounds__(128) void panel_trsm(float* __restrict__ K, int k)
{
  int lz = blockIdx.y;
  float* A = K + (size_t)lz * NN * NN;
  __shared__ float Ld[64][65];
  __shared__ float invd[64];
  __shared__ float P[128][65];
  int tid = threadIdx.x;
  for (int t = tid; t < 4096; t += 128)
    Ld[t >> 6][t & 63] = A[(size_t)(k + (t >> 6)) * NN + k + (t & 63)];
  int rbase = k + NB + blockIdx.x * 128;
  for (int t = tid; t < 128 * 64; t += 128) {
    int r = t >> 6, c = t & 63;
    if (rbase + r < NN) P[r][c] = A[(size_t)(rbase + r) * NN + k + c];
  }
  __syncthreads();
  if (tid < 64) invd[tid] = 1.0f / Ld[tid][tid];
  __syncthreads();
  int r = tid;
  if (rbase + r < NN) {
    for (int j = 0; j < 64; ++j) {
      float acc = P[r][j];
      for (int p = 0; p < j; ++p) acc -= Ld[j][p] * P[r][p];
      P[r][j] = acc * invd[j];
    }
  }
  __syncthreads();
  for (int t = tid; t < 128 * 64; t += 128) {
    int rr = t >> 6, c = t & 63;
    if (rbase + rr < NN) A[(size_t)(rbase + rr) * NN + k + c] = P[rr][c];
  }
}

// ---------------- Cholesky: trailing update  A22 -= L21 * L21^T ----------------
__global__ __launch_bounds__(256) void syrk_update(float* __restrict__ K, int k)
{
  if (blockIdx.y > blockIdx.x) return;          // lower tiles only
  int lz = blockIdx.z;
  float* A = K + (size_t)lz * NN * NN;
  int i0 = k + NB + blockIdx.x * 64;
  int j0 = k + NB + blockIdx.y * 64;
  __shared__ __align__(16) float Asub[64][68];
  __shared__ __align__(16) float Bsub[64][68];
  int tid = threadIdx.x;
  for (int t = tid; t < 4096; t += 256) {
    int r = t >> 6, c = t & 63;
    Asub[r][c] = A[(size_t)(i0 + r) * NN + k + c];
    Bsub[r][c] = A[(size_t)(j0 + r) * NN + k + c];
  }
  __syncthreads();
  int tx = tid & 15, ty = tid >> 4;
  float acc[4][4] = {{0.f}};
  #pragma unroll
  for (int p4 = 0; p4 < 16; ++p4) {
    float4 av[4], bv[4];
    #pragma unroll
    for (int ii = 0; ii < 4; ++ii) av[ii] = *(const float4*)&Asub[ty*4+ii][p4*4];
    #pragma unroll
    for (int jj = 0; jj < 4; ++jj) bv[jj] = *(const float4*)&Bsub[tx*4+jj][p4*4];
    #pragma unroll
    for (int ii = 0; ii < 4; ++ii)
      #pragma unroll
      for (int jj = 0; jj < 4; ++jj)
        acc[ii][jj] += av[ii].x*bv[jj].x + av[ii].y*bv[jj].y
                     + av[ii].z*bv[jj].z + av[ii].w*bv[jj].w;
  }
  #pragma unroll
  for (int ii = 0; ii < 4; ++ii) {
    int row = i0 + ty*4 + ii;
    float4* cp = (float4*)&A[(size_t)row * NN + j0 + tx*4];
    float4 cv = *cp;
    cv.x -= acc[ii][0]; cv.y -= acc[ii][1]; cv.z -= acc[ii][2]; cv.w -= acc[ii][3];
    *cp = cv;
  }
}

// ============ stepped TRSM, NB=128 per step ============
// forward diag: solve L[kb:kb+128, kb:kb+128] * y = rhs (in place on Y rows kb..kb+127)
__global__ __launch_bounds__(512) void trsm_diag_fwd(
    const float* __restrict__ K, float* __restrict__ Y, int kb)
{
  int lz = blockIdx.x;
  const float* L = K + (size_t)lz * NN * NN;
  float* y = Y + (size_t)lz * NN * HD;
  __shared__ float Ld1[64][65];
  __shared__ float L21[64][65];
  __shared__ float Ld2[64][65];
  __shared__ float yb[128][HD];
  int tid = threadIdx.x;
  for (int t = tid; t < 4096; t += 512) {
    int r = t >> 6, c = t & 63;
    Ld1[r][c] = L[(size_t)(kb + r) * NN + kb + c];
    L21[r][c] = L[(size_t)(kb + 64 + r) * NN + kb + c];
    Ld2[r][c] = L[(size_t)(kb + 64 + r) * NN + kb + 64 + c];
  }
  for (int t = tid; t < 128 * HD; t += 512)
    yb[t >> 4][t & 15] = y[(size_t)kb * HD + t];
  __syncthreads();
  if (tid < HD) {                       // solve top 64
    int c = tid;
    for (int j = 0; j < 64; ++j) {
      float acc = yb[j][c];
      for (int p = 0; p < j; ++p) acc -= Ld1[j][p] * yb[p][c];
      yb[j][c] = acc / Ld1[j][j];
    }
  }
  __syncthreads();
  {                                     // mid update: yb[64+r] -= L21[r,:] @ yb[0:64]
    int o = tid;                        // 1024 outputs over 512 threads, 2 each
    #pragma unroll
    for (int q = 0; q < 2; ++q, o += 512) {
      int r = o >> 4, c = o & 15;
      float acc = 0.f;
      #pragma unroll 16
      for (int p = 0; p < 64; ++p) acc += L21[r][p] * yb[p][c];
      yb[64 + r][c] -= acc;
    }
  }
  __syncthreads();
  if (tid < HD) {                       // solve bottom 64
    int c = tid;
    for (int j = 0; j < 64; ++j) {
      float acc = yb[64 + j][c];
      for (int p = 0; p < j; ++p) acc -= Ld2[j][p] * yb[64 + p][c];
      yb[64 + j][c] = acc / Ld2[j][j];
    }
  }
  __syncthreads();
  for (int t = tid; t < 128 * HD; t += 512)
    y[(size_t)kb * HD + t] = yb[t >> 4][t & 15];
}

// forward update: Y[i0..i0+63] -= L[i0.., kb:kb+128] @ Y[kb:kb+128]
__global__ __launch_bounds__(256) void trsm_upd_fwd(
    const float* __restrict__ K, float* __restrict__ Y, int kb)
{
  int lz = blockIdx.y;
  const float* L = K + (size_t)lz * NN * NN;
  float* y = Y + (size_t)lz * NN * HD;
  int i0 = kb + 128 + blockIdx.x * 64;
  __shared__ float Lt[64][129];
  __shared__ __align__(16) float yk[128][HD];
  int tid = threadIdx.x;
  for (int e = tid; e < 64 * 128; e += 256) {
    int r = e >> 7, p = e & 127;
    Lt[r][p] = L[(size_t)(i0 + r) * NN + kb + p];
  }
  for (int e = tid; e < 128 * HD; e += 256)
    yk[e >> 4][e & 15] = y[(size_t)kb * HD + e];
  __syncthreads();
  int row = tid & 63, cg = tid >> 6;    // 4 col-groups of 4
  float4 acc = make_float4(0.f, 0.f, 0.f, 0.f);
  #pragma unroll 8
  for (int p = 0; p < 128; ++p) {
    float l = Lt[row][p];
    float4 yv = *(const float4*)&yk[p][cg * 4];
    acc.x += l * yv.x; acc.y += l * yv.y; acc.z += l * yv.z; acc.w += l * yv.w;
  }
  float4* yp = (float4*)&y[(size_t)(i0 + row) * HD + cg * 4];
  float4 cv = *yp;
  cv.x -= acc.x; cv.y -= acc.y; cv.z -= acc.z; cv.w -= acc.w;
  *yp = cv;
}

// backward diag: solve L^T on rows kb..kb+127 (in place)
__global__ __launch_bounds__(512) void trsm_diag_bwd(
    const float* __restrict__ K, float* __restrict__ Y, int kb)
{
  int lz = blockIdx.x;
  const float* L = K + (size_t)lz * NN * NN;
  float* y = Y + (size_t)lz * NN * HD;
  __shared__ float Ld1[64][65];
  __shared__ float L21[64][65];
  __shared__ float Ld2[64][65];
  __shared__ float yb[128][HD];
  int tid = threadIdx.x;
  for (int t = tid; t < 4096; t += 512) {
    int r = t >> 6, c = t & 63;
    Ld1[r][c] = L[(size_t)(kb + r) * NN + kb + c];
    L21[r][c] = L[(size_t)(kb + 64 + r) * NN + kb + c];
    Ld2[r][c] = L[(size_t)(kb + 64 + r) * NN + kb + 64 + c];
  }
  for (int t = tid; t < 128 * HD; t += 512)
    yb[t >> 4][t & 15] = y[(size_t)kb * HD + t];
  __syncthreads();
  if (tid < HD) {                       // solve bottom 64 with Ld2^T
    int c = tid;
    for (int j = 63; j >= 0; --j) {
      float acc = yb[64 + j][c];
      for (int p = j + 1; p < 64; ++p) acc -= Ld2[p][j] * yb[64 + p][c];
      yb[64 + j][c] = acc / Ld2[j][j];
    }
  }
  __syncthreads();
  {                                     // top update: yb[r] -= L21[:,r]^T @ yb[64:128]
    int o = tid;
    #pragma unroll
    for (int q = 0; q < 2; ++q, o += 512) {
      int r = o >> 4, c = o & 15;
      float acc = 0.f;
      #pragma unroll 16
      for (int p = 0; p < 64; ++p) acc += L21[p][r] * yb[64 + p][c];
      yb[r][c] -= acc;
    }
  }
  __syncthreads();
  if (tid < HD) {                       // solve top 64 with Ld1^T
    int c = tid;
    for (int j = 63; j >= 0; --j) {
      float acc = yb[j][c];
      for (int p = j + 1; p < 64; ++p) acc -= Ld1[p][j] * yb[p][c];
      yb[j][c] = acc / Ld1[j][j];
    }
  }
  __syncthreads();
  for (int t = tid; t < 128 * HD; t += 512)
    y[(size_t)kb * HD + t] = yb[t >> 4][t & 15];
}

// backward update: Y[i0..i0+63] -= L[kb:kb+128, i0..]^T @ Y[kb:kb+128]
__global__ __launch_bounds__(256) void trsm_upd_bwd(
    const float* __restrict__ K, float* __restrict__ Y, int kb)
{
  int lz = blockIdx.y;
  const float* L = K + (size_t)lz * NN * NN;
  float* y = Y + (size_t)lz * NN * HD;
  int i0 = blockIdx.x * 64;             // rows above kb
  __shared__ float Lt[64][129];
  __shared__ __align__(16) float yk[128][HD];
  int tid = threadIdx.x;
  for (int e = tid; e < 64 * 128; e += 256) {
    int p = e >> 6, r = e & 63;         // read coalesced along r
    Lt[r][p] = L[(size_t)(kb + p) * NN + i0 + r];
  }
  for (int e = tid; e < 128 * HD; e += 256)
    yk[e >> 4][e & 15] = y[(size_t)kb * HD + e];
  __syncthreads();
  int row = tid & 63, cg = tid >> 6;
  float4 acc = make_float4(0.f, 0.f, 0.f, 0.f);
  #pragma unroll 8
  for (int p = 0; p < 128; ++p) {
    float l = Lt[row][p];
    float4 yv = *(const float4*)&yk[p][cg * 4];
    acc.x += l * yv.x; acc.y += l * yv.y; acc.z += l * yv.z; acc.w += l * yv.w;
  }
  float4* yp = (float4*)&y[(size_t)(i0 + row) * HD + cg * 4];
  float4 cv = *yp;
  cv.x -= acc.x; cv.y -= acc.y; cv.z -= acc.z; cv.w -= acc.w;
  *yp = cv;
}

// ---------------- fused h^T[l*16+hh][i] = (K_tx @ a)  ----------------
__global__ __launch_bounds__(256) void compute_h(
    const float* __restrict__ x, const float* __restrict__ tp,
    const float* __restrict__ A, const float* __restrict__ sigma,
    float* __restrict__ Ht, int N)
{
  int l = blockIdx.y;
  const float* xt = tp + (size_t)l * NN * 3;
  const float* al = A + (size_t)l * NN * HD;
  float inv_sigma = 1.0f / sigma[l];
  int tid = threadIdx.x;
  int r0 = blockIdx.x * 512 + tid;
  int r1 = r0 + 256;
  float x00=0.f,x01=0.f,x02=0.f, x10=0.f,x11=0.f,x12=0.f;
  if (r0 < N) { x00 = x[r0*3]; x01 = x[r0*3+1]; x02 = x[r0*3+2]; }
  if (r1 < N) { x10 = x[r1*3]; x11 = x[r1*3+1]; x12 = x[r1*3+2]; }
  __shared__ float sxt[128*3];
  __shared__ __align__(16) float sa[128*16];
  float acc0[16] = {0.f}; float acc1[16] = {0.f};
  for (int jc = 0; jc < NN; jc += 128) {
    __syncthreads();
    for (int t = tid; t < 384; t += 256)  sxt[t] = xt[jc*3 + t];
    for (int t = tid; t < 2048; t += 256) sa[t]  = al[jc*16 + t];
    __syncthreads();
    for (int jl = 0; jl < 128; ++jl) {
      float t0 = sxt[jl*3+0], t1 = sxt[jl*3+1], t2 = sxt[jl*3+2];
      float da = x00 - t0, db = x01 - t1, dc = x02 - t2;
      float d20 = da*da + db*db + dc*dc;
      da = x10 - t0; db = x11 - t1; dc = x12 - t2;
      float d21 = da*da + db*db + dc*dc;
      float k0 = __expf(-sqrtf(fmaxf(d20, 1e-12f)) * inv_sigma);
      float k1 = __expf(-sqrtf(fmaxf(d21, 1e-12f)) * inv_sigma);
      const float4* a4 = (const float4*)&sa[jl*16];
      #pragma unroll
      for (int q = 0; q < 4; ++q) {
        float4 av = a4[q];
        acc0[q*4+0] += k0*av.x; acc0[q*4+1] += k0*av.y;
        acc0[q*4+2] += k0*av.z; acc0[q*4+3] += k0*av.w;
        acc1[q*4+0] += k1*av.x; acc1[q*4+1] += k1*av.y;
        acc1[q*4+2] += k1*av.z; acc1[q*4+3] += k1*av.w;
      }
    }
  }
  if (r0 < N) {
    #pragma unroll
    for (int hh = 0; hh < 16; ++hh) Ht[(size_t)(l*HD + hh) * N + r0] = acc0[hh];
  }
  if (r1 < N) {
    #pragma unroll
    for (int hh = 0; hh < 16; ++hh) Ht[(size_t)(l*HD + hh) * N + r1] = acc1[hh];
  }
}

// ---------------- MLP 112->40->40->40->40->1, weights in LDS ----------------
__global__ __launch_bounds__(256) void mlp_kernel(
    const float* __restrict__ Ht,
    const float* __restrict__ w1, const float* __restrict__ b1,
    const float* __restrict__ w2, const float* __restrict__ b2,
    const float* __restrict__ w3, const float* __restrict__ b3,
    const float* __restrict__ w4, const float* __restrict__ b4,
    const float* __restrict__ w5, const float* __restrict__ b5,
    float* __restrict__ out, int N)
{
  __shared__ __align__(16) float W1[HTOT*40];
  __shared__ __align__(16) float W2[1600];
  __shared__ __align__(16) float W3[1600];
  __shared__ __align__(16) float W4[1600];
  __shared__ float W5[40], B1[40], B2[40], B3[40], B4[40];
  __shared__ float B5s;
  int tid = threadIdx.x;
  for (int t = tid; t < HTOT*40; t += 256) W1[t] = w1[t];
  for (int t = tid; t < 1600; t += 256) { W2[t] = w2[t]; W3[t] = w3[t]; W4[t] = w4[t]; }
  if (tid < 40) { B1[tid]=b1[tid]; B2[tid]=b2[tid]; B3[tid]=b3[tid]; B4[tid]=b4[tid]; W5[tid]=w5[tid]; }
  if (tid == 0) B5s = b5[0];
  __syncthreads();
  int r = blockIdx.x * 256 + tid;
  if (r >= N) return;

  float za[40], zb[40];
  #pragma unroll
  for (int o = 0; o < 40; ++o) za[o] = B1[o];
  for (int i = 0; i < HTOT; ++i) {
    float hv = Ht[(size_t)i * N + r];
    const float4* wp = (const float4*)&W1[i*40];
    #pragma unroll
    for (int q = 0; q < 10; ++q) {
      float4 wv = wp[q];
      za[q*4+0] += hv*wv.x; za[q*4+1] += hv*wv.y; za[q*4+2] += hv*wv.z; za[q*4+3] += hv*wv.w;
    }
  }
  #pragma unroll
  for (int o = 0; o < 40; ++o) { za[o] = fmaxf(za[o], 0.f); zb[o] = B2[o]; }
  for (int i = 0; i < 40; ++i) {
    float hv = za[i];
    const float4* wp = (const float4*)&W2[i*40];
    #pragma unroll
    for (int q = 0; q < 10; ++q) {
      float4 wv = wp[q];
      zb[q*4+0] += hv*wv.x; zb[q*4+1] += hv*wv.y; zb[q*4+2] += hv*wv.z; zb[q*4+3] += hv*wv.w;
    }
  }
  #pragma unroll
  for (int o = 0; o < 40; ++o) { zb[o] = fmaxf(zb[o], 0.f); za[o] = B3[o]; }
  for (int i = 0; i < 40; ++i) {
    float hv = zb[i];
    const float4* wp = (const float4*)&W3[i*40];
    #pragma unroll
    for (int q = 0; q < 10; ++q) {
      float4 wv = wp[q];
      za[q*4+0] += hv*wv.x; za[q*4+1] += hv*wv.y; za[q*4+2] += hv*wv.z; za[q*4+3] += hv*wv.w;
    }
  }
  #pragma unroll
  for (int o = 0; o < 40; ++o) { za[o] = fmaxf(za[o], 0.f); zb[o] = B4[o]; }
  for (int i = 0; i < 40; ++i) {
    float hv = za[i];
    const float4* wp = (const float4*)&W4[i*40];
    #pragma unroll
    for (int q = 0; q < 10; ++q) {
      float4 wv = wp[q];
      zb[q*4+0] += hv*wv.x; zb[q*4+1] += hv*wv.y; zb[q*4+2] += hv*wv.z; zb[q*4+3] += hv*wv.w;
    }
  }
  float ov = B5s;
  #pragma unroll
  for (int o = 0; o < 40; ++o) ov += fmaxf(zb[o], 0.f) * W5[o];
  out[r] = ov;
}

// ---------------- host ----------------
static void run_chol_steps(float* K, int nl, hipStream_t stream)
{
  for (int k = 0; k < NN; k += NB) {
    chol_diag<<<nl, 64, 0, stream>>>(K, k);
    int m = NN - k - NB;
    if (m > 0) {
      panel_trsm<<<dim3((m + 127) / 128, nl), 128, 0, stream>>>(K, k);
      int t = m / 64;
      syrk_update<<<dim3(t, t, nl), 256, 0, stream>>>(K, k);
    }
  }
}

static void run_trsm_steps(const float* K, float* Y, int nl, hipStream_t stream)
{
  for (int kb = 0; kb < NN; kb += 128) {
    trsm_diag_fwd<<<nl, 512, 0, stream>>>(K, Y, kb);
    int m = NN - kb - 128;
    if (m > 0)
      trsm_upd_fwd<<<dim3(m / 64, nl), 256, 0, stream>>>(K, Y, kb);
  }
  for (int kb = NN - 128; kb >= 0; kb -= 128) {
    trsm_diag_bwd<<<nl, 512, 0, stream>>>(K, Y, kb);
    if (kb > 0)
      trsm_upd_bwd<<<dim3(kb / 64, nl), 256, 0, stream>>>(K, Y, kb);
  }
}

extern "C" void kernel_launch(void* const* d_in, const int* in_sizes, int n_in,
                              void* d_out, int out_size, void* d_ws, size_t ws_size,
                              hipStream_t stream)
{
  (void)n_in; (void)out_size;
  const float* x     = (const float*)d_in[0];
  const float* tp    = (const float*)d_in[1];
  const float* W     = (const float*)d_in[2];
  const float* alpha = (const float*)d_in[3];
  const float* sigma = (const float*)d_in[4];
  const float* w1 = (const float*)d_in[5];  const float* b1 = (const float*)d_in[6];
  const float* w2 = (const float*)d_in[7];  const float* b2 = (const float*)d_in[8];
  const float* w3 = (const float*)d_in[9];  const float* b3 = (const float*)d_in[10];
  const float* w4 = (const float*)d_in[11]; const float* b4 = (const float*)d_in[12];
  const float* w5 = (const float*)d_in[13]; const float* b5 = (const float*)d_in[14];
  float* out = (float*)d_out;
  int N = in_sizes[0] / 3;

  size_t kElems1 = (size_t)NN * NN;
  size_t aElems  = (size_t)NLVL * NN * HD;
  size_t hElems  = (size_t)N * HTOT;
  size_t need7   = (7 * kElems1 + aElems + hElems) * sizeof(float);
  bool batched = ws_size >= need7;
  int nlK = batched ? NLVL : 1;

  float* K = (float*)d_ws;
  float* A = K + (size_t)nlK * kElems1;   // solve RHS, becomes 'a' in place
  float* H = A + aElems;                  // transposed h: [112][N]

  hipMemcpyAsync(A, W, aElems * sizeof(float), hipMemcpyDeviceToDevice, stream);

  if (batched) {
    build_K<<<dim3((unsigned)(kElems1 / 256), NLVL), 256, 0, stream>>>(tp, alpha, sigma, K, 0);
    run_chol_steps(K, NLVL, stream);
    run_trsm_steps(K, A, NLVL, stream);
  } else {
    for (int l = 0; l < NLVL; ++l) {
      build_K<<<dim3((unsigned)(kElems1 / 256), 1), 256, 0, stream>>>(tp, alpha, sigma, K, l);
      run_chol_steps(K, 1, stream);
      run_trsm_steps(K, A + (size_t)l * NN * HD, 1, stream);
    }
  }

  compute_h<<<dim3((N + 511) / 512, NLVL), 256, 0, stream>>>(x, tp, A, sigma, H, N);
  mlp_kernel<<<(N + 255) / 256, 256, 0, stream>>>(H, w1, b1, w2, b2, w3, b3, w4, b4, w5, b5, out, N);
}